// Round 1
// baseline (463.590 us; speedup 1.0000x reference)
//
#include <hip/hip_runtime.h>
#include <hip/hip_bf16.h>

#define N_TOK 4096
#define D_MODEL 1024
#define D_FF 2048
#define N_EXP 8

typedef __attribute__((ext_vector_type(8))) short short8;
typedef __attribute__((ext_vector_type(4))) float f32x4;

// ---- workspace layout (bytes) ----
#define OFF_COUNTS 0              // 8 int
#define OFF_BASE   64             // 8 int
#define OFF_TOK    4096           // 8*4096 int
#define OFF_SLOT   135168         // 8*4096 int
#define OFF_GATE   266240         // 8*4096 float
#define OFF_LOADV  397312         // 4096*8 float
#define OFF_XB     1048576        // 4096*1024 bf16 (8 MB)
#define OFF_W1T    9437184        // 8*2048*1024 bf16 (32 MB)  [n][k] layout
#define OFF_W2T    42991616       // 8*1024*2048 bf16 (32 MB)  [n][k] layout
#define OFF_H      76546048       // 8192*2048 bf16 (32 MB)
#define OFF_SOUT   110100480      // 2*4096*1024 float (32 MB)
// total: 143654912 bytes (~137 MB)

__device__ __forceinline__ unsigned short f2bf(float f) {
  union { float f; unsigned u; } a; a.f = f;
  return (unsigned short)((a.u + 0x7FFFu + ((a.u >> 16) & 1u)) >> 16);
}

// ---- x -> bf16, also zero the expert counters ----
__global__ __launch_bounds__(256) void convert_x_kernel(
    const float* __restrict__ x, unsigned short* __restrict__ xb, int* counts) {
  if (blockIdx.x == 0 && threadIdx.x < N_EXP) counts[threadIdx.x] = 0;
  const int i = blockIdx.x * 256 + threadIdx.x;     // 1M float4 groups
  float4 v = ((const float4*)x)[i];
  ushort4 o;
  o.x = f2bf(v.x); o.y = f2bf(v.y); o.z = f2bf(v.z); o.w = f2bf(v.w);
  ((ushort4*)xb)[i] = o;
}

// ---- fp32 [E][K][N] -> bf16 [E][N][K] (transpose for MFMA B-operand) ----
__global__ __launch_bounds__(256) void transpose_bf16_kernel(
    const float* __restrict__ in, unsigned short* __restrict__ out, int K, int N) {
  __shared__ float tile[32][33];
  const int e = blockIdx.z;
  const int kb = blockIdx.y * 32, nb = blockIdx.x * 32;
  const int c = threadIdx.x & 31, r0 = threadIdx.x >> 5;   // c:0..31, r0:0..7
  const float* ine = in + (size_t)e * K * N;
  unsigned short* oute = out + (size_t)e * K * N;
#pragma unroll
  for (int i = 0; i < 4; ++i)
    tile[r0 + i * 8][c] = ine[(size_t)(kb + r0 + i * 8) * N + nb + c];
  __syncthreads();
#pragma unroll
  for (int i = 0; i < 4; ++i)
    oute[(size_t)(nb + r0 + i * 8) * K + kb + c] = f2bf(tile[c][r0 + i * 8]);
}

// ---- noisy top-k gating: one wave per token ----
__global__ __launch_bounds__(256) void gating_kernel(
    const float* __restrict__ x, const float* __restrict__ noise,
    const float* __restrict__ wg, const float* __restrict__ wn,
    int* __restrict__ counts, int* __restrict__ tok_list,
    int* __restrict__ slot_list, float* __restrict__ gate_list,
    float* __restrict__ loadvec) {
  const int wave = threadIdx.x >> 6, lane = threadIdx.x & 63;
  const int t = blockIdx.x * 4 + wave;
  float ag[8], an[8];
#pragma unroll
  for (int e = 0; e < 8; ++e) { ag[e] = 0.f; an[e] = 0.f; }
  const float* xrow = x + (size_t)t * D_MODEL;
  for (int d = lane; d < D_MODEL; d += 64) {
    const float xv = xrow[d];
    const float4 wa = ((const float4*)(wg + (size_t)d * 8))[0];
    const float4 wb = ((const float4*)(wg + (size_t)d * 8))[1];
    const float4 na = ((const float4*)(wn + (size_t)d * 8))[0];
    const float4 nb = ((const float4*)(wn + (size_t)d * 8))[1];
    ag[0] += xv * wa.x; ag[1] += xv * wa.y; ag[2] += xv * wa.z; ag[3] += xv * wa.w;
    ag[4] += xv * wb.x; ag[5] += xv * wb.y; ag[6] += xv * wb.z; ag[7] += xv * wb.w;
    an[0] += xv * na.x; an[1] += xv * na.y; an[2] += xv * na.z; an[3] += xv * na.w;
    an[4] += xv * nb.x; an[5] += xv * nb.y; an[6] += xv * nb.z; an[7] += xv * nb.w;
  }
#pragma unroll
  for (int e = 0; e < 8; ++e) {
#pragma unroll
    for (int off = 32; off > 0; off >>= 1) {
      ag[e] += __shfl_xor(ag[e], off, 64);
      an[e] += __shfl_xor(an[e], off, 64);
    }
  }
  // every lane now holds full sums; compute gating redundantly
  float clean[8], sd[8], nz[8];
#pragma unroll
  for (int e = 0; e < 8; ++e) {
    clean[e] = ag[e];
    float s = an[e];
    s = (s > 20.f) ? s : log1pf(expf(s));          // softplus
    sd[e] = s + 0.01f;                              // + noise_eps
    nz[e] = clean[e] + noise[t * 8 + e] * sd[e];
  }
  float v0 = -1e30f, v1 = -1e30f, v2 = -1e30f; int i0 = 0, i1 = 0;
#pragma unroll
  for (int e = 0; e < 8; ++e) {
    const float v = nz[e];
    if (v > v0)      { v2 = v1; v1 = v0; i1 = i0; v0 = v; i0 = e; }
    else if (v > v1) { v2 = v1; v1 = v; i1 = e; }
    else if (v > v2) { v2 = v; }
  }
  const float ex = expf(v1 - v0);
  const float g0 = 1.f / (1.f + ex);
  const float g1 = ex / (1.f + ex);
  if (lane == 0) {
    const int p0 = atomicAdd(&counts[i0], 1);
    tok_list[i0 * N_TOK + p0] = t; slot_list[i0 * N_TOK + p0] = 0; gate_list[i0 * N_TOK + p0] = g0;
    const int p1 = atomicAdd(&counts[i1], 1);
    tok_list[i1 * N_TOK + p1] = t; slot_list[i1 * N_TOK + p1] = 1; gate_list[i1 * N_TOK + p1] = g1;
  }
  if (lane < 8) {
    const int e = lane;
    const bool is_in = nz[e] > v2;          // v2 = (k+1)-th noisy value
    const float thr = is_in ? v2 : v1;      // v1 = k-th noisy value
    const float z = (clean[e] - thr) / sd[e];
    loadvec[t * 8 + e] = 0.5f * erfcf(-z * 0.70710678118654752f);  // norm.cdf
  }
}

// ---- loss (cv^2, ddof=1) + exclusive scan of counts -> base ----
__global__ __launch_bounds__(256) void loss_scan_kernel(
    const int* __restrict__ counts, int* __restrict__ base,
    const float* __restrict__ gate_list, const float* __restrict__ loadvec,
    float* __restrict__ loss_out) {
  float limp[8], lld[8];
#pragma unroll
  for (int e = 0; e < 8; ++e) { limp[e] = 0.f; lld[e] = 0.f; }
  for (int e = 0; e < 8; ++e) {
    const int c = counts[e];
    for (int p = threadIdx.x; p < c; p += 256) limp[e] += gate_list[e * N_TOK + p];
  }
  for (int t = threadIdx.x; t < N_TOK; t += 256) {
#pragma unroll
    for (int e = 0; e < 8; ++e) lld[e] += loadvec[t * 8 + e];
  }
#pragma unroll
  for (int e = 0; e < 8; ++e) {
#pragma unroll
    for (int off = 32; off > 0; off >>= 1) {
      limp[e] += __shfl_xor(limp[e], off, 64);
      lld[e]  += __shfl_xor(lld[e],  off, 64);
    }
  }
  __shared__ float red[4][16];
  const int wave = threadIdx.x >> 6, lane = threadIdx.x & 63;
  if (lane == 0) {
#pragma unroll
    for (int e = 0; e < 8; ++e) { red[wave][e] = limp[e]; red[wave][8 + e] = lld[e]; }
  }
  __syncthreads();
  if (threadIdx.x == 0) {
    double imp[8], ld[8];
    for (int e = 0; e < 8; ++e) {
      imp[e] = (double)red[0][e] + red[1][e] + red[2][e] + red[3][e];
      ld[e]  = (double)red[0][8 + e] + red[1][8 + e] + red[2][8 + e] + red[3][8 + e];
    }
    double mi = 0, ml = 0;
    for (int e = 0; e < 8; ++e) { mi += imp[e]; ml += ld[e]; }
    mi /= 8.0; ml /= 8.0;
    double vi = 0, vl = 0;
    for (int e = 0; e < 8; ++e) { vi += (imp[e] - mi) * (imp[e] - mi); vl += (ld[e] - ml) * (ld[e] - ml); }
    vi /= 7.0; vl /= 7.0;
    const double loss = 0.1 * (vi / (mi * mi + 1e-10) + vl / (ml * ml + 1e-10));
    loss_out[0] = (float)loss;
    int b = 0;
    for (int e = 0; e < 8; ++e) { base[e] = b; b += counts[e]; }
  }
}

// ---- GEMM1: h[base+m][f] = relu(x[tok(m)] @ w1[e] + b1[e]), bf16 MFMA ----
__global__ __launch_bounds__(256) void gemm1_kernel(
    const unsigned short* __restrict__ xb, const unsigned short* __restrict__ w1t,
    const float* __restrict__ b1,
    const int* __restrict__ counts, const int* __restrict__ base,
    const int* __restrict__ tok_list, unsigned short* __restrict__ h) {
  const int e = blockIdx.z, mt = blockIdx.y, nt = blockIdx.x;
  const int cnt = counts[e];
  const int m0 = mt * 128;
  if (m0 >= cnt) return;
  const int n0 = nt * 128;
  const int bs = base[e];

  __shared__ __align__(16) unsigned short As[128 * 72];  // 64 k + 8 pad per row
  __shared__ __align__(16) unsigned short Bs[128 * 72];

  const int tid = threadIdx.x;
  const int srow = tid >> 1, shalf = tid & 1;
  const int arow = min(m0 + srow, cnt - 1);
  const int tok = tok_list[e * N_TOK + arow];
  const uint4* asrc = (const uint4*)(xb + (size_t)tok * D_MODEL + shalf * 32);
  const uint4* bsrc = (const uint4*)(w1t + (size_t)e * D_MODEL * D_FF + (size_t)(n0 + srow) * D_MODEL + shalf * 32);
  uint4* adst = (uint4*)(As + srow * 72 + shalf * 32);
  uint4* bdst = (uint4*)(Bs + srow * 72 + shalf * 32);

  const int wave = tid >> 6, lane = tid & 63;
  const int wm = wave & 1, wn = wave >> 1;
  const int q = lane >> 4, r = lane & 15;

  f32x4 acc[4][4];
#pragma unroll
  for (int a = 0; a < 4; ++a)
#pragma unroll
    for (int b = 0; b < 4; ++b) acc[a][b] = (f32x4){0.f, 0.f, 0.f, 0.f};

  for (int k0 = 0; k0 < D_MODEL; k0 += 64) {
    const int kq = k0 >> 3;
#pragma unroll
    for (int c = 0; c < 4; ++c) adst[c] = asrc[kq + c];
#pragma unroll
    for (int c = 0; c < 4; ++c) bdst[c] = bsrc[kq + c];
    __syncthreads();
#pragma unroll
    for (int kk = 0; kk < 64; kk += 32) {
      short8 af[4], bfg[4];
#pragma unroll
      for (int t = 0; t < 4; ++t)
        af[t] = *(const short8*)(As + (wm * 64 + t * 16 + r) * 72 + kk + q * 8);
#pragma unroll
      for (int t = 0; t < 4; ++t)
        bfg[t] = *(const short8*)(Bs + (wn * 64 + t * 16 + r) * 72 + kk + q * 8);
#pragma unroll
      for (int tm = 0; tm < 4; ++tm)
#pragma unroll
        for (int tn = 0; tn < 4; ++tn)
          acc[tm][tn] = __builtin_amdgcn_mfma_f32_16x16x32_bf16(af[tm], bfg[tn], acc[tm][tn], 0, 0, 0);
    }
    __syncthreads();
  }

  float bv[4];
#pragma unroll
  for (int tn = 0; tn < 4; ++tn) bv[tn] = b1[e * D_FF + n0 + wn * 64 + tn * 16 + r];
#pragma unroll
  for (int tm = 0; tm < 4; ++tm) {
#pragma unroll
    for (int v = 0; v < 4; ++v) {
      const int i = wm * 64 + tm * 16 + q * 4 + v;
      if (m0 + i < cnt) {
        unsigned short* hrow = h + (size_t)(bs + m0 + i) * D_FF + n0 + wn * 64 + r;
#pragma unroll
        for (int tn = 0; tn < 4; ++tn)
          hrow[tn * 16] = f2bf(fmaxf(acc[tm][tn][v] + bv[tn], 0.f));
      }
    }
  }
}

// ---- GEMM2: sout[slot][tok][d] = gate * (h[row] @ w2[e] + b2[e]) ----
__global__ __launch_bounds__(256) void gemm2_kernel(
    const unsigned short* __restrict__ h, const unsigned short* __restrict__ w2t,
    const float* __restrict__ b2,
    const int* __restrict__ counts, const int* __restrict__ base,
    const int* __restrict__ tok_list, const int* __restrict__ slot_list,
    const float* __restrict__ gate_list, float* __restrict__ sout) {
  const int e = blockIdx.z, mt = blockIdx.y, nt = blockIdx.x;
  const int cnt = counts[e];
  const int m0 = mt * 128;
  if (m0 >= cnt) return;
  const int n0 = nt * 128;
  const int bs = base[e];

  __shared__ __align__(16) unsigned short As[128 * 72];
  __shared__ __align__(16) unsigned short Bs[128 * 72];

  const int tid = threadIdx.x;
  const int srow = tid >> 1, shalf = tid & 1;
  const int arow = min(m0 + srow, cnt - 1);
  const uint4* asrc = (const uint4*)(h + (size_t)(bs + arow) * D_FF + shalf * 32);
  const uint4* bsrc = (const uint4*)(w2t + (size_t)e * D_MODEL * D_FF + (size_t)(n0 + srow) * D_FF + shalf * 32);
  uint4* adst = (uint4*)(As + srow * 72 + shalf * 32);
  uint4* bdst = (uint4*)(Bs + srow * 72 + shalf * 32);

  const int wave = tid >> 6, lane = tid & 63;
  const int wm = wave & 1, wn = wave >> 1;
  const int q = lane >> 4, r = lane & 15;

  f32x4 acc[4][4];
#pragma unroll
  for (int a = 0; a < 4; ++a)
#pragma unroll
    for (int b = 0; b < 4; ++b) acc[a][b] = (f32x4){0.f, 0.f, 0.f, 0.f};

  for (int k0 = 0; k0 < D_FF; k0 += 64) {
    const int kq = k0 >> 3;
#pragma unroll
    for (int c = 0; c < 4; ++c) adst[c] = asrc[kq + c];
#pragma unroll
    for (int c = 0; c < 4; ++c) bdst[c] = bsrc[kq + c];
    __syncthreads();
#pragma unroll
    for (int kk = 0; kk < 64; kk += 32) {
      short8 af[4], bfg[4];
#pragma unroll
      for (int t = 0; t < 4; ++t)
        af[t] = *(const short8*)(As + (wm * 64 + t * 16 + r) * 72 + kk + q * 8);
#pragma unroll
      for (int t = 0; t < 4; ++t)
        bfg[t] = *(const short8*)(Bs + (wn * 64 + t * 16 + r) * 72 + kk + q * 8);
#pragma unroll
      for (int tm = 0; tm < 4; ++tm)
#pragma unroll
        for (int tn = 0; tn < 4; ++tn)
          acc[tm][tn] = __builtin_amdgcn_mfma_f32_16x16x32_bf16(af[tm], bfg[tn], acc[tm][tn], 0, 0, 0);
    }
    __syncthreads();
  }

  float bv[4];
#pragma unroll
  for (int tn = 0; tn < 4; ++tn) bv[tn] = b2[e * D_MODEL + n0 + wn * 64 + tn * 16 + r];
#pragma unroll
  for (int tm = 0; tm < 4; ++tm) {
#pragma unroll
    for (int v = 0; v < 4; ++v) {
      const int i = wm * 64 + tm * 16 + q * 4 + v;
      const int mrow = m0 + i;
      if (mrow < cnt) {
        const int idx = e * N_TOK + mrow;
        const int tok = tok_list[idx];
        const int sl = slot_list[idx];
        const float g = gate_list[idx];
        float* orow = sout + ((size_t)sl * N_TOK + tok) * D_MODEL + n0 + wn * 64 + r;
#pragma unroll
        for (int tn = 0; tn < 4; ++tn)
          orow[tn * 16] = (acc[tm][tn][v] + bv[tn]) * g;
      }
    }
  }
}

// ---- combine the two expert-slot contributions, zero-fill with eps ----
__global__ __launch_bounds__(256) void combine_kernel(
    const float* __restrict__ sout, float* __restrict__ y) {
  const int i = blockIdx.x * 256 + threadIdx.x;
  const float4 a = ((const float4*)sout)[i];
  const float4 b = ((const float4*)(sout + (size_t)N_TOK * D_MODEL))[i];
  float4 o;
  o.x = a.x + b.x; o.y = a.y + b.y; o.z = a.z + b.z; o.w = a.w + b.w;
  const float eps = 2.2204460492503131e-16f;
  if (o.x == 0.f) o.x = eps;
  if (o.y == 0.f) o.y = eps;
  if (o.z == 0.f) o.z = eps;
  if (o.w == 0.f) o.w = eps;
  ((float4*)y)[i] = o;
}

extern "C" void kernel_launch(void* const* d_in, const int* in_sizes, int n_in,
                              void* d_out, int out_size, void* d_ws, size_t ws_size,
                              hipStream_t stream) {
  const float* x     = (const float*)d_in[0];
  const float* noise = (const float*)d_in[1];
  const float* wg    = (const float*)d_in[2];
  const float* wn    = (const float*)d_in[3];
  const float* w1    = (const float*)d_in[4];
  const float* b1    = (const float*)d_in[5];
  const float* w2    = (const float*)d_in[6];
  const float* b2    = (const float*)d_in[7];
  float* out = (float*)d_out;

  char* ws = (char*)d_ws;
  int*   counts    = (int*)(ws + OFF_COUNTS);
  int*   base      = (int*)(ws + OFF_BASE);
  int*   tok_list  = (int*)(ws + OFF_TOK);
  int*   slot_list = (int*)(ws + OFF_SLOT);
  float* gate_list = (float*)(ws + OFF_GATE);
  float* loadvec   = (float*)(ws + OFF_LOADV);
  unsigned short* xb  = (unsigned short*)(ws + OFF_XB);
  unsigned short* w1t = (unsigned short*)(ws + OFF_W1T);
  unsigned short* w2t = (unsigned short*)(ws + OFF_W2T);
  unsigned short* h   = (unsigned short*)(ws + OFF_H);
  float* sout = (float*)(ws + OFF_SOUT);

  // x -> bf16 (+ zero counts)
  convert_x_kernel<<<4096, 256, 0, stream>>>(x, xb, counts);
  // w1 [E][1024][2048] -> w1t [E][2048][1024] bf16
  transpose_bf16_kernel<<<dim3(D_FF / 32, D_MODEL / 32, N_EXP), 256, 0, stream>>>(w1, w1t, D_MODEL, D_FF);
  // w2 [E][2048][1024] -> w2t [E][1024][2048] bf16
  transpose_bf16_kernel<<<dim3(D_MODEL / 32, D_FF / 32, N_EXP), 256, 0, stream>>>(w2, w2t, D_FF, D_MODEL);
  // gating: one wave per token
  gating_kernel<<<N_TOK / 4, 256, 0, stream>>>(x, noise, wg, wn, counts, tok_list,
                                               slot_list, gate_list, loadvec);
  // loss + base scan (writes out[4096*1024])
  loss_scan_kernel<<<1, 256, 0, stream>>>(counts, base, gate_list, loadvec,
                                          out + (size_t)N_TOK * D_MODEL);
  // expert FFN layer 1: h = relu(x_gathered @ w1 + b1)
  gemm1_kernel<<<dim3(D_FF / 128, N_TOK / 128, N_EXP), 256, 0, stream>>>(
      xb, w1t, b1, counts, base, tok_list, h);
  // expert FFN layer 2: sout[slot] = gate * (h @ w2 + b2)
  gemm2_kernel<<<dim3(D_MODEL / 128, N_TOK / 128, N_EXP), 256, 0, stream>>>(
      h, w2t, b2, counts, base, tok_list, slot_list, gate_list, sout);
  // y = sout0 + sout1, zero-fill eps
  combine_kernel<<<(N_TOK * D_MODEL / 4) / 256, 256, 0, stream>>>(sout, out);
}

// Round 2
// 399.289 us; speedup vs baseline: 1.1610x; 1.1610x over previous
//
#include <hip/hip_runtime.h>
#include <hip/hip_bf16.h>

#define N_TOK 4096
#define D_MODEL 1024
#define D_FF 2048
#define N_EXP 8

typedef __attribute__((ext_vector_type(8))) short short8;
typedef __attribute__((ext_vector_type(4))) float f32x4;

// ---- workspace layout (bytes) ----
#define OFF_COUNTS 0              // 8 int
#define OFF_BASE   64             // 8 int
#define OFF_SEL    128            // 4096 int   (e0 | e1<<8)
#define OFF_G0     16512          // 4096 float (gate of top-1; top-2 gate = 1-g0)
#define OFF_TOK    32896          // 8*4096 int
#define OFF_SLOT   163968         // 8*4096 int
#define OFF_GATE   295040         // 8*4096 float
#define OFF_LOADV  426112         // 4096*8 float
#define OFF_XB     1048576        // 4096*1024 bf16 (8 MB)
#define OFF_W1T    9437184        // 8*2048*1024 bf16 (32 MB)  [n][k]
#define OFF_W2T    42991616       // 8*1024*2048 bf16 (32 MB)  [n][k]
#define OFF_H      76546048       // 8192*2048 bf16 (32 MB)
#define OFF_SOUT   110100480      // 2*4096*1024 float (32 MB)
// total: 143654912 bytes (~137 MB)

__device__ __forceinline__ unsigned short f2bf(float f) {
  union { float f; unsigned u; } a; a.f = f;
  return (unsigned short)((a.u + 0x7FFFu + ((a.u >> 16) & 1u)) >> 16);
}

// async global -> LDS, 16B per lane; lds dst must be the wave-uniform base
__device__ __forceinline__ void async16(const void* g, void* l) {
  __builtin_amdgcn_global_load_lds(
      (const __attribute__((address_space(1))) unsigned int*)g,
      (__attribute__((address_space(3))) unsigned int*)l, 16, 0, 0);
}

// ---- x -> bf16, also zero the expert counters ----
__global__ __launch_bounds__(256) void convert_x_kernel(
    const float* __restrict__ x, unsigned short* __restrict__ xb, int* counts) {
  if (blockIdx.x == 0 && threadIdx.x < N_EXP) counts[threadIdx.x] = 0;
  const int i = blockIdx.x * 256 + threadIdx.x;     // 1M float4 groups
  float4 v = ((const float4*)x)[i];
  ushort4 o;
  o.x = f2bf(v.x); o.y = f2bf(v.y); o.z = f2bf(v.z); o.w = f2bf(v.w);
  ((ushort4*)xb)[i] = o;
}

// ---- fp32 [E][K][N] -> bf16 [E][N][K] (transpose for MFMA B-operand) ----
__global__ __launch_bounds__(256) void transpose_bf16_kernel(
    const float* __restrict__ in, unsigned short* __restrict__ out, int K, int N) {
  __shared__ float tile[32][33];
  const int e = blockIdx.z;
  const int kb = blockIdx.y * 32, nb = blockIdx.x * 32;
  const int c = threadIdx.x & 31, r0 = threadIdx.x >> 5;   // c:0..31, r0:0..7
  const float* ine = in + (size_t)e * K * N;
  unsigned short* oute = out + (size_t)e * K * N;
#pragma unroll
  for (int i = 0; i < 4; ++i)
    tile[r0 + i * 8][c] = ine[(size_t)(kb + r0 + i * 8) * N + nb + c];
  __syncthreads();
#pragma unroll
  for (int i = 0; i < 4; ++i)
    oute[(size_t)(nb + r0 + i * 8) * K + kb + c] = f2bf(tile[c][r0 + i * 8]);
}

// ---- noisy top-k gating: one wave per token, NO global atomics ----
__global__ __launch_bounds__(256) void gating_kernel(
    const float* __restrict__ x, const float* __restrict__ noise,
    const float* __restrict__ wg, const float* __restrict__ wn,
    int* __restrict__ sel, float* __restrict__ g0out,
    float* __restrict__ loadvec) {
  const int wave = threadIdx.x >> 6, lane = threadIdx.x & 63;
  const int t = blockIdx.x * 4 + wave;
  float ag[8], an[8];
#pragma unroll
  for (int e = 0; e < 8; ++e) { ag[e] = 0.f; an[e] = 0.f; }
  const float* xrow = x + (size_t)t * D_MODEL;
  for (int d = lane; d < D_MODEL; d += 64) {
    const float xv = xrow[d];
    const float4 wa = ((const float4*)(wg + (size_t)d * 8))[0];
    const float4 wb = ((const float4*)(wg + (size_t)d * 8))[1];
    const float4 na = ((const float4*)(wn + (size_t)d * 8))[0];
    const float4 nb = ((const float4*)(wn + (size_t)d * 8))[1];
    ag[0] += xv * wa.x; ag[1] += xv * wa.y; ag[2] += xv * wa.z; ag[3] += xv * wa.w;
    ag[4] += xv * wb.x; ag[5] += xv * wb.y; ag[6] += xv * wb.z; ag[7] += xv * wb.w;
    an[0] += xv * na.x; an[1] += xv * na.y; an[2] += xv * na.z; an[3] += xv * na.w;
    an[4] += xv * nb.x; an[5] += xv * nb.y; an[6] += xv * nb.z; an[7] += xv * nb.w;
  }
#pragma unroll
  for (int e = 0; e < 8; ++e) {
#pragma unroll
    for (int off = 32; off > 0; off >>= 1) {
      ag[e] += __shfl_xor(ag[e], off, 64);
      an[e] += __shfl_xor(an[e], off, 64);
    }
  }
  float clean[8], sd[8], nz[8];
#pragma unroll
  for (int e = 0; e < 8; ++e) {
    clean[e] = ag[e];
    float s = an[e];
    s = (s > 20.f) ? s : log1pf(expf(s));          // softplus
    sd[e] = s + 0.01f;                              // + noise_eps
    nz[e] = clean[e] + noise[t * 8 + e] * sd[e];
  }
  float v0 = -1e30f, v1 = -1e30f, v2 = -1e30f; int i0 = 0, i1 = 0;
#pragma unroll
  for (int e = 0; e < 8; ++e) {
    const float v = nz[e];
    if (v > v0)      { v2 = v1; v1 = v0; i1 = i0; v0 = v; i0 = e; }
    else if (v > v1) { v2 = v1; v1 = v; i1 = e; }
    else if (v > v2) { v2 = v; }
  }
  const float ex = expf(v1 - v0);
  const float g0 = 1.f / (1.f + ex);
  if (lane == 0) { sel[t] = i0 | (i1 << 8); g0out[t] = g0; }
  if (lane < 8) {
    const int e = lane;
    const bool is_in = nz[e] > v2;          // v2 = (k+1)-th noisy value
    const float thr = is_in ? v2 : v1;      // v1 = k-th noisy value
    const float z = (clean[e] - thr) / sd[e];
    loadvec[t * 8 + e] = 0.5f * erfcf(-z * 0.70710678118654752f);  // norm.cdf
  }
}

// ---- build per-expert token lists: LDS histogram, 8 global atomics/block ----
__global__ __launch_bounds__(256) void build_lists_kernel(
    const int* __restrict__ sel, const float* __restrict__ g0a,
    int* __restrict__ counts, int* __restrict__ tok_list,
    int* __restrict__ slot_list, float* __restrict__ gate_list) {
  __shared__ int hist[8], bbase[8];
  if (threadIdx.x < 8) hist[threadIdx.x] = 0;
  __syncthreads();
  const int t = blockIdx.x * 256 + threadIdx.x;
  const int s = sel[t];
  const int e0 = s & 255, e1 = (s >> 8) & 255;
  atomicAdd(&hist[e0], 1);
  atomicAdd(&hist[e1], 1);
  __syncthreads();
  if (threadIdx.x < 8) {
    bbase[threadIdx.x] = atomicAdd(&counts[threadIdx.x], hist[threadIdx.x]);
    hist[threadIdx.x] = 0;
  }
  __syncthreads();
  const float g = g0a[t];
  const int p0 = atomicAdd(&hist[e0], 1);
  const int idx0 = e0 * N_TOK + bbase[e0] + p0;
  tok_list[idx0] = t; slot_list[idx0] = 0; gate_list[idx0] = g;
  const int p1 = atomicAdd(&hist[e1], 1);
  const int idx1 = e1 * N_TOK + bbase[e1] + p1;
  tok_list[idx1] = t; slot_list[idx1] = 1; gate_list[idx1] = 1.f - g;
}

// ---- loss (cv^2, ddof=1) + exclusive scan of counts -> base ----
__global__ __launch_bounds__(256) void loss_scan_kernel(
    const int* __restrict__ counts, int* __restrict__ base,
    const int* __restrict__ sel, const float* __restrict__ g0a,
    const float* __restrict__ loadvec, float* __restrict__ loss_out) {
  float limp[8], lld[8];
#pragma unroll
  for (int e = 0; e < 8; ++e) { limp[e] = 0.f; lld[e] = 0.f; }
  for (int t = threadIdx.x; t < N_TOK; t += 256) {
    const int s = sel[t];
    const float g = g0a[t];
    const int e0 = s & 255, e1 = (s >> 8) & 255;
#pragma unroll
    for (int e = 0; e < 8; ++e)
      limp[e] += (e0 == e ? g : 0.f) + (e1 == e ? (1.f - g) : 0.f);
#pragma unroll
    for (int e = 0; e < 8; ++e) lld[e] += loadvec[t * 8 + e];
  }
#pragma unroll
  for (int e = 0; e < 8; ++e) {
#pragma unroll
    for (int off = 32; off > 0; off >>= 1) {
      limp[e] += __shfl_xor(limp[e], off, 64);
      lld[e]  += __shfl_xor(lld[e],  off, 64);
    }
  }
  __shared__ float red[4][16];
  const int wave = threadIdx.x >> 6, lane = threadIdx.x & 63;
  if (lane == 0) {
#pragma unroll
    for (int e = 0; e < 8; ++e) { red[wave][e] = limp[e]; red[wave][8 + e] = lld[e]; }
  }
  __syncthreads();
  if (threadIdx.x == 0) {
    double imp[8], ld[8];
    for (int e = 0; e < 8; ++e) {
      imp[e] = (double)red[0][e] + red[1][e] + red[2][e] + red[3][e];
      ld[e]  = (double)red[0][8 + e] + red[1][8 + e] + red[2][8 + e] + red[3][8 + e];
    }
    double mi = 0, ml = 0;
    for (int e = 0; e < 8; ++e) { mi += imp[e]; ml += ld[e]; }
    mi /= 8.0; ml /= 8.0;
    double vi = 0, vl = 0;
    for (int e = 0; e < 8; ++e) { vi += (imp[e] - mi) * (imp[e] - mi); vl += (ld[e] - ml) * (ld[e] - ml); }
    vi /= 7.0; vl /= 7.0;
    const double loss = 0.1 * (vi / (mi * mi + 1e-10) + vl / (ml * ml + 1e-10));
    loss_out[0] = (float)loss;
    int b = 0;
    for (int e = 0; e < 8; ++e) { base[e] = b; b += counts[e]; }
  }
}

// ---- GEMM1: h[base+m][f] = relu(x[tok(m)] @ w1[e] + b1[e]) ----
// m97 structure: 128x128 tile, BK=64, global_load_lds dwordx4, unpadded LDS
__global__ __launch_bounds__(256) void gemm1_kernel(
    const unsigned short* __restrict__ xb, const unsigned short* __restrict__ w1t,
    const float* __restrict__ b1,
    const int* __restrict__ counts, const int* __restrict__ base,
    const int* __restrict__ tok_list, unsigned short* __restrict__ h) {
  const int e = blockIdx.z, mt = blockIdx.y, nt = blockIdx.x;
  const int cnt = counts[e];
  const int m0 = mt * 128;
  if (m0 >= cnt) return;
  const int n0 = nt * 128;
  const int bs = base[e];

  __shared__ __align__(16) unsigned short As[128 * 64];
  __shared__ __align__(16) unsigned short Bs[128 * 64];

  const int tid = threadIdx.x;
  const int wave = tid >> 6, lane = tid & 63;
  const int lrow = lane >> 3;            // 0..7
  const int lcol = (lane & 7) * 8;       // 0,8,..,56 (16B groups)

  const unsigned short* ap[4];
  const unsigned short* bp[4];
  unsigned short* adst[4];
  unsigned short* bdst[4];
#pragma unroll
  for (int c = 0; c < 4; ++c) {
    const int rr = wave * 32 + c * 8;
    const int arow = min(m0 + rr + lrow, cnt - 1);
    const int tok = tok_list[e * N_TOK + arow];
    ap[c] = xb + (size_t)tok * D_MODEL + lcol;
    bp[c] = w1t + (size_t)e * D_MODEL * D_FF + (size_t)(n0 + rr + lrow) * D_MODEL + lcol;
    adst[c] = As + rr * 64;              // wave-uniform; HW adds lane*16B
    bdst[c] = Bs + rr * 64;
  }

  const int wm = wave & 1, wn = wave >> 1;
  const int q = lane >> 4, r = lane & 15;

  f32x4 acc[4][4];
#pragma unroll
  for (int a = 0; a < 4; ++a)
#pragma unroll
    for (int b = 0; b < 4; ++b) acc[a][b] = (f32x4){0.f, 0.f, 0.f, 0.f};

  for (int k0 = 0; k0 < D_MODEL; k0 += 64) {
#pragma unroll
    for (int c = 0; c < 4; ++c) {
      async16(ap[c], adst[c]);
      async16(bp[c], bdst[c]);
      ap[c] += 64; bp[c] += 64;
    }
    __syncthreads();
#pragma unroll
    for (int kk = 0; kk < 64; kk += 32) {
      short8 af[4], bfg[4];
#pragma unroll
      for (int t = 0; t < 4; ++t)
        af[t] = *(const short8*)(As + (wm * 64 + t * 16 + r) * 64 + kk + q * 8);
#pragma unroll
      for (int t = 0; t < 4; ++t)
        bfg[t] = *(const short8*)(Bs + (wn * 64 + t * 16 + r) * 64 + kk + q * 8);
#pragma unroll
      for (int tm = 0; tm < 4; ++tm)
#pragma unroll
        for (int tn = 0; tn < 4; ++tn)
          acc[tm][tn] = __builtin_amdgcn_mfma_f32_16x16x32_bf16(af[tm], bfg[tn], acc[tm][tn], 0, 0, 0);
    }
    __syncthreads();
  }

  float bv[4];
#pragma unroll
  for (int tn = 0; tn < 4; ++tn) bv[tn] = b1[e * D_FF + n0 + wn * 64 + tn * 16 + r];
#pragma unroll
  for (int tm = 0; tm < 4; ++tm) {
#pragma unroll
    for (int v = 0; v < 4; ++v) {
      const int i = wm * 64 + tm * 16 + q * 4 + v;
      if (m0 + i < cnt) {
        unsigned short* hrow = h + (size_t)(bs + m0 + i) * D_FF + n0 + wn * 64 + r;
#pragma unroll
        for (int tn = 0; tn < 4; ++tn)
          hrow[tn * 16] = f2bf(fmaxf(acc[tm][tn][v] + bv[tn], 0.f));
      }
    }
  }
}

// ---- GEMM2: sout[slot][tok][d] = gate * (h[row] @ w2[e] + b2[e]) ----
__global__ __launch_bounds__(256) void gemm2_kernel(
    const unsigned short* __restrict__ h, const unsigned short* __restrict__ w2t,
    const float* __restrict__ b2,
    const int* __restrict__ counts, const int* __restrict__ base,
    const int* __restrict__ tok_list, const int* __restrict__ slot_list,
    const float* __restrict__ gate_list, float* __restrict__ sout) {
  const int e = blockIdx.z, mt = blockIdx.y, nt = blockIdx.x;
  const int cnt = counts[e];
  const int m0 = mt * 128;
  if (m0 >= cnt) return;
  const int n0 = nt * 128;
  const int bs = base[e];

  __shared__ __align__(16) unsigned short As[128 * 64];
  __shared__ __align__(16) unsigned short Bs[128 * 64];

  const int tid = threadIdx.x;
  const int wave = tid >> 6, lane = tid & 63;
  const int lrow = lane >> 3;
  const int lcol = (lane & 7) * 8;

  const unsigned short* ap[4];
  const unsigned short* bp[4];
  unsigned short* adst[4];
  unsigned short* bdst[4];
#pragma unroll
  for (int c = 0; c < 4; ++c) {
    const int rr = wave * 32 + c * 8;
    const int arow = min(m0 + rr + lrow, cnt - 1);
    ap[c] = h + (size_t)(bs + arow) * D_FF + lcol;
    bp[c] = w2t + (size_t)e * D_MODEL * D_FF + (size_t)(n0 + rr + lrow) * D_FF + lcol;
    adst[c] = As + rr * 64;
    bdst[c] = Bs + rr * 64;
  }

  const int wm = wave & 1, wn = wave >> 1;
  const int q = lane >> 4, r = lane & 15;

  f32x4 acc[4][4];
#pragma unroll
  for (int a = 0; a < 4; ++a)
#pragma unroll
    for (int b = 0; b < 4; ++b) acc[a][b] = (f32x4){0.f, 0.f, 0.f, 0.f};

  for (int k0 = 0; k0 < D_FF; k0 += 64) {
#pragma unroll
    for (int c = 0; c < 4; ++c) {
      async16(ap[c], adst[c]);
      async16(bp[c], bdst[c]);
      ap[c] += 64; bp[c] += 64;
    }
    __syncthreads();
#pragma unroll
    for (int kk = 0; kk < 64; kk += 32) {
      short8 af[4], bfg[4];
#pragma unroll
      for (int t = 0; t < 4; ++t)
        af[t] = *(const short8*)(As + (wm * 64 + t * 16 + r) * 64 + kk + q * 8);
#pragma unroll
      for (int t = 0; t < 4; ++t)
        bfg[t] = *(const short8*)(Bs + (wn * 64 + t * 16 + r) * 64 + kk + q * 8);
#pragma unroll
      for (int tm = 0; tm < 4; ++tm)
#pragma unroll
        for (int tn = 0; tn < 4; ++tn)
          acc[tm][tn] = __builtin_amdgcn_mfma_f32_16x16x32_bf16(af[tm], bfg[tn], acc[tm][tn], 0, 0, 0);
    }
    __syncthreads();
  }

  float bv[4];
#pragma unroll
  for (int tn = 0; tn < 4; ++tn) bv[tn] = b2[e * D_MODEL + n0 + wn * 64 + tn * 16 + r];
#pragma unroll
  for (int tm = 0; tm < 4; ++tm) {
#pragma unroll
    for (int v = 0; v < 4; ++v) {
      const int i = wm * 64 + tm * 16 + q * 4 + v;
      const int mrow = m0 + i;
      if (mrow < cnt) {
        const int idx = e * N_TOK + mrow;
        const int tok = tok_list[idx];
        const int sl = slot_list[idx];
        const float g = gate_list[idx];
        float* orow = sout + ((size_t)sl * N_TOK + tok) * D_MODEL + n0 + wn * 64 + r;
#pragma unroll
        for (int tn = 0; tn < 4; ++tn)
          orow[tn * 16] = (acc[tm][tn][v] + bv[tn]) * g;
      }
    }
  }
}

// ---- combine the two expert-slot contributions, zero-fill with eps ----
__global__ __launch_bounds__(256) void combine_kernel(
    const float* __restrict__ sout, float* __restrict__ y) {
  const int i = blockIdx.x * 256 + threadIdx.x;
  const float4 a = ((const float4*)sout)[i];
  const float4 b = ((const float4*)(sout + (size_t)N_TOK * D_MODEL))[i];
  float4 o;
  o.x = a.x + b.x; o.y = a.y + b.y; o.z = a.z + b.z; o.w = a.w + b.w;
  const float eps = 2.2204460492503131e-16f;
  if (o.x == 0.f) o.x = eps;
  if (o.y == 0.f) o.y = eps;
  if (o.z == 0.f) o.z = eps;
  if (o.w == 0.f) o.w = eps;
  ((float4*)y)[i] = o;
}

extern "C" void kernel_launch(void* const* d_in, const int* in_sizes, int n_in,
                              void* d_out, int out_size, void* d_ws, size_t ws_size,
                              hipStream_t stream) {
  const float* x     = (const float*)d_in[0];
  const float* noise = (const float*)d_in[1];
  const float* wg    = (const float*)d_in[2];
  const float* wn    = (const float*)d_in[3];
  const float* w1    = (const float*)d_in[4];
  const float* b1    = (const float*)d_in[5];
  const float* w2    = (const float*)d_in[6];
  const float* b2    = (const float*)d_in[7];
  float* out = (float*)d_out;

  char* ws = (char*)d_ws;
  int*   counts    = (int*)(ws + OFF_COUNTS);
  int*   base      = (int*)(ws + OFF_BASE);
  int*   sel       = (int*)(ws + OFF_SEL);
  float* g0a       = (float*)(ws + OFF_G0);
  int*   tok_list  = (int*)(ws + OFF_TOK);
  int*   slot_list = (int*)(ws + OFF_SLOT);
  float* gate_list = (float*)(ws + OFF_GATE);
  float* loadvec   = (float*)(ws + OFF_LOADV);
  unsigned short* xb  = (unsigned short*)(ws + OFF_XB);
  unsigned short* w1t = (unsigned short*)(ws + OFF_W1T);
  unsigned short* w2t = (unsigned short*)(ws + OFF_W2T);
  unsigned short* h   = (unsigned short*)(ws + OFF_H);
  float* sout = (float*)(ws + OFF_SOUT);

  convert_x_kernel<<<4096, 256, 0, stream>>>(x, xb, counts);
  transpose_bf16_kernel<<<dim3(D_FF / 32, D_MODEL / 32, N_EXP), 256, 0, stream>>>(w1, w1t, D_MODEL, D_FF);
  transpose_bf16_kernel<<<dim3(D_MODEL / 32, D_FF / 32, N_EXP), 256, 0, stream>>>(w2, w2t, D_FF, D_MODEL);
  gating_kernel<<<N_TOK / 4, 256, 0, stream>>>(x, noise, wg, wn, sel, g0a, loadvec);
  build_lists_kernel<<<N_TOK / 256, 256, 0, stream>>>(sel, g0a, counts, tok_list, slot_list, gate_list);
  loss_scan_kernel<<<1, 256, 0, stream>>>(counts, base, sel, g0a, loadvec,
                                          out + (size_t)N_TOK * D_MODEL);
  gemm1_kernel<<<dim3(D_FF / 128, N_TOK / 128, N_EXP), 256, 0, stream>>>(
      xb, w1t, b1, counts, base, tok_list, h);
  gemm2_kernel<<<dim3(D_MODEL / 128, N_TOK / 128, N_EXP), 256, 0, stream>>>(
      h, w2t, b2, counts, base, tok_list, slot_list, gate_list, sout);
  combine_kernel<<<(N_TOK * D_MODEL / 4) / 256, 256, 0, stream>>>(sout, out);
}

// Round 3
// 358.621 us; speedup vs baseline: 1.2927x; 1.1134x over previous
//
#include <hip/hip_runtime.h>
#include <hip/hip_bf16.h>

#define N_TOK 4096
#define D_MODEL 1024
#define D_FF 2048
#define N_EXP 8

typedef __attribute__((ext_vector_type(8))) short short8;
typedef __attribute__((ext_vector_type(4))) float f32x4;

// ---- workspace layout (bytes) ----
#define OFF_COUNTS 0              // 8 int
#define OFF_BASE   64             // 8 int
#define OFF_SEL    128            // 4096 int   (e0 | e1<<8)
#define OFF_G0     16512          // 4096 float
#define OFF_TOK    32896          // 8*4096 int
#define OFF_SLOT   163968         // 8*4096 int
#define OFF_GATE   295040         // 8*4096 float
#define OFF_LOADV  426112         // 4096*8 float
#define OFF_XB     1048576        // 4096*1024 bf16 (8 MB)
#define OFF_W1T    9437184        // 8*2048*1024 bf16 (32 MB)  [n][k]
#define OFF_W2T    42991616       // 8*1024*2048 bf16 (32 MB)  [n][k]
#define OFF_H      76546048       // 8192*2048 bf16 (32 MB)
#define OFF_SOUT   110100480      // 2*4096*1024 float (32 MB)

__device__ __forceinline__ unsigned short f2bf(float f) {
  union { float f; unsigned u; } a; a.f = f;
  return (unsigned short)((a.u + 0x7FFFu + ((a.u >> 16) & 1u)) >> 16);
}

// async global -> LDS, 16B/lane; LDS dst = wave-uniform base (+ lane*16 by HW)
__device__ __forceinline__ void async16(const void* g, void* l) {
  __builtin_amdgcn_global_load_lds(
      (const __attribute__((address_space(1))) unsigned int*)g,
      (__attribute__((address_space(3))) unsigned int*)l, 16, 0, 0);
}

__global__ __launch_bounds__(256) void convert_x_kernel(
    const float* __restrict__ x, unsigned short* __restrict__ xb, int* counts) {
  if (blockIdx.x == 0 && threadIdx.x < N_EXP) counts[threadIdx.x] = 0;
  const int i = blockIdx.x * 256 + threadIdx.x;
  float4 v = ((const float4*)x)[i];
  ushort4 o;
  o.x = f2bf(v.x); o.y = f2bf(v.y); o.z = f2bf(v.z); o.w = f2bf(v.w);
  ((ushort4*)xb)[i] = o;
}

__global__ __launch_bounds__(256) void transpose_bf16_kernel(
    const float* __restrict__ in, unsigned short* __restrict__ out, int K, int N) {
  __shared__ float tile[32][33];
  const int e = blockIdx.z;
  const int kb = blockIdx.y * 32, nb = blockIdx.x * 32;
  const int c = threadIdx.x & 31, r0 = threadIdx.x >> 5;
  const float* ine = in + (size_t)e * K * N;
  unsigned short* oute = out + (size_t)e * K * N;
#pragma unroll
  for (int i = 0; i < 4; ++i)
    tile[r0 + i * 8][c] = ine[(size_t)(kb + r0 + i * 8) * N + nb + c];
  __syncthreads();
#pragma unroll
  for (int i = 0; i < 4; ++i)
    oute[(size_t)(nb + r0 + i * 8) * K + kb + c] = f2bf(tile[c][r0 + i * 8]);
}

__global__ __launch_bounds__(256) void gating_kernel(
    const float* __restrict__ x, const float* __restrict__ noise,
    const float* __restrict__ wg, const float* __restrict__ wn,
    int* __restrict__ sel, float* __restrict__ g0out,
    float* __restrict__ loadvec) {
  const int wave = threadIdx.x >> 6, lane = threadIdx.x & 63;
  const int t = blockIdx.x * 4 + wave;
  float ag[8], an[8];
#pragma unroll
  for (int e = 0; e < 8; ++e) { ag[e] = 0.f; an[e] = 0.f; }
  const float* xrow = x + (size_t)t * D_MODEL;
  for (int d = lane; d < D_MODEL; d += 64) {
    const float xv = xrow[d];
    const float4 wa = ((const float4*)(wg + (size_t)d * 8))[0];
    const float4 wb = ((const float4*)(wg + (size_t)d * 8))[1];
    const float4 na = ((const float4*)(wn + (size_t)d * 8))[0];
    const float4 nb = ((const float4*)(wn + (size_t)d * 8))[1];
    ag[0] += xv * wa.x; ag[1] += xv * wa.y; ag[2] += xv * wa.z; ag[3] += xv * wa.w;
    ag[4] += xv * wb.x; ag[5] += xv * wb.y; ag[6] += xv * wb.z; ag[7] += xv * wb.w;
    an[0] += xv * na.x; an[1] += xv * na.y; an[2] += xv * na.z; an[3] += xv * na.w;
    an[4] += xv * nb.x; an[5] += xv * nb.y; an[6] += xv * nb.z; an[7] += xv * nb.w;
  }
#pragma unroll
  for (int e = 0; e < 8; ++e) {
#pragma unroll
    for (int off = 32; off > 0; off >>= 1) {
      ag[e] += __shfl_xor(ag[e], off, 64);
      an[e] += __shfl_xor(an[e], off, 64);
    }
  }
  float clean[8], sd[8], nz[8];
#pragma unroll
  for (int e = 0; e < 8; ++e) {
    clean[e] = ag[e];
    float s = an[e];
    s = (s > 20.f) ? s : log1pf(expf(s));
    sd[e] = s + 0.01f;
    nz[e] = clean[e] + noise[t * 8 + e] * sd[e];
  }
  float v0 = -1e30f, v1 = -1e30f, v2 = -1e30f; int i0 = 0, i1 = 0;
#pragma unroll
  for (int e = 0; e < 8; ++e) {
    const float v = nz[e];
    if (v > v0)      { v2 = v1; v1 = v0; i1 = i0; v0 = v; i0 = e; }
    else if (v > v1) { v2 = v1; v1 = v; i1 = e; }
    else if (v > v2) { v2 = v; }
  }
  const float ex = expf(v1 - v0);
  const float g0 = 1.f / (1.f + ex);
  if (lane == 0) { sel[t] = i0 | (i1 << 8); g0out[t] = g0; }
  if (lane < 8) {
    const int e = lane;
    const bool is_in = nz[e] > v2;
    const float thr = is_in ? v2 : v1;
    const float z = (clean[e] - thr) / sd[e];
    loadvec[t * 8 + e] = 0.5f * erfcf(-z * 0.70710678118654752f);
  }
}

__global__ __launch_bounds__(256) void build_lists_kernel(
    const int* __restrict__ sel, const float* __restrict__ g0a,
    int* __restrict__ counts, int* __restrict__ tok_list,
    int* __restrict__ slot_list, float* __restrict__ gate_list) {
  __shared__ int hist[8], bbase[8];
  if (threadIdx.x < 8) hist[threadIdx.x] = 0;
  __syncthreads();
  const int t = blockIdx.x * 256 + threadIdx.x;
  const int s = sel[t];
  const int e0 = s & 255, e1 = (s >> 8) & 255;
  atomicAdd(&hist[e0], 1);
  atomicAdd(&hist[e1], 1);
  __syncthreads();
  if (threadIdx.x < 8) {
    bbase[threadIdx.x] = atomicAdd(&counts[threadIdx.x], hist[threadIdx.x]);
    hist[threadIdx.x] = 0;
  }
  __syncthreads();
  const float g = g0a[t];
  const int p0 = atomicAdd(&hist[e0], 1);
  const int idx0 = e0 * N_TOK + bbase[e0] + p0;
  tok_list[idx0] = t; slot_list[idx0] = 0; gate_list[idx0] = g;
  const int p1 = atomicAdd(&hist[e1], 1);
  const int idx1 = e1 * N_TOK + bbase[e1] + p1;
  tok_list[idx1] = t; slot_list[idx1] = 1; gate_list[idx1] = 1.f - g;
}

__global__ __launch_bounds__(256) void loss_scan_kernel(
    const int* __restrict__ counts, int* __restrict__ base,
    const int* __restrict__ sel, const float* __restrict__ g0a,
    const float* __restrict__ loadvec, float* __restrict__ loss_out) {
  float limp[8], lld[8];
#pragma unroll
  for (int e = 0; e < 8; ++e) { limp[e] = 0.f; lld[e] = 0.f; }
  for (int t = threadIdx.x; t < N_TOK; t += 256) {
    const int s = sel[t];
    const float g = g0a[t];
    const int e0 = s & 255, e1 = (s >> 8) & 255;
#pragma unroll
    for (int e = 0; e < 8; ++e)
      limp[e] += (e0 == e ? g : 0.f) + (e1 == e ? (1.f - g) : 0.f);
#pragma unroll
    for (int e = 0; e < 8; ++e) lld[e] += loadvec[t * 8 + e];
  }
#pragma unroll
  for (int e = 0; e < 8; ++e) {
#pragma unroll
    for (int off = 32; off > 0; off >>= 1) {
      limp[e] += __shfl_xor(limp[e], off, 64);
      lld[e]  += __shfl_xor(lld[e],  off, 64);
    }
  }
  __shared__ float red[4][16];
  const int wave = threadIdx.x >> 6, lane = threadIdx.x & 63;
  if (lane == 0) {
#pragma unroll
    for (int e = 0; e < 8; ++e) { red[wave][e] = limp[e]; red[wave][8 + e] = lld[e]; }
  }
  __syncthreads();
  if (threadIdx.x == 0) {
    double imp[8], ld[8];
    for (int e = 0; e < 8; ++e) {
      imp[e] = (double)red[0][e] + red[1][e] + red[2][e] + red[3][e];
      ld[e]  = (double)red[0][8 + e] + red[1][8 + e] + red[2][8 + e] + red[3][8 + e];
    }
    double mi = 0, ml = 0;
    for (int e = 0; e < 8; ++e) { mi += imp[e]; ml += ld[e]; }
    mi /= 8.0; ml /= 8.0;
    double vi = 0, vl = 0;
    for (int e = 0; e < 8; ++e) { vi += (imp[e] - mi) * (imp[e] - mi); vl += (ld[e] - ml) * (ld[e] - ml); }
    vi /= 7.0; vl /= 7.0;
    const double loss = 0.1 * (vi / (mi * mi + 1e-10) + vl / (ml * ml + 1e-10));
    loss_out[0] = (float)loss;
    int b = 0;
    for (int e = 0; e < 8; ++e) { base[e] = b; b += counts[e]; }
  }
}

// ---- GEMM1: h = relu(gather(x) @ w1[e] + b1[e]) ----
// blockIdx: x=expert (XCD affinity), y=nt, z=mt.
// LDS layout: row-major 128x64, column-group cg (16B) XOR-swizzled by row&7.
__global__ __launch_bounds__(256) void gemm1_kernel(
    const unsigned short* __restrict__ xb, const unsigned short* __restrict__ w1t,
    const float* __restrict__ b1,
    const int* __restrict__ counts, const int* __restrict__ base,
    const int* __restrict__ tok_list, unsigned short* __restrict__ h) {
  const int e = blockIdx.x, nt = blockIdx.y, mt = blockIdx.z;
  const int cnt = counts[e];
  const int m0 = mt * 128;
  if (m0 >= cnt) return;
  const int n0 = nt * 128;
  const int bs = base[e];

  __shared__ __align__(16) unsigned short As[128 * 64];
  __shared__ __align__(16) unsigned short Bs[128 * 64];

  const int tid = threadIdx.x;
  const int wave = tid >> 6, lane = tid & 63;
  const int lrow = lane >> 3;            // 0..7
  const int scg  = (lane & 7) ^ lrow;    // swizzled source column-group

  const unsigned short* ap[4];
  const unsigned short* bp[4];
  unsigned short* adst[4];
  unsigned short* bdst[4];
#pragma unroll
  for (int c = 0; c < 4; ++c) {
    const int rr = wave * 32 + c * 8;
    const int arow = min(m0 + rr + lrow, cnt - 1);
    const int tok = tok_list[e * N_TOK + arow];
    ap[c] = xb + (size_t)tok * D_MODEL + scg * 8;
    bp[c] = w1t + (size_t)e * D_MODEL * D_FF + (size_t)(n0 + rr + lrow) * D_MODEL + scg * 8;
    adst[c] = As + rr * 64;
    bdst[c] = Bs + rr * 64;
  }

  const int wm = wave & 1, wn = wave >> 1;
  const int q = lane >> 4, r = lane & 15;
  const int r7 = r & 7;

  f32x4 acc[4][4];
#pragma unroll
  for (int a = 0; a < 4; ++a)
#pragma unroll
    for (int b = 0; b < 4; ++b) acc[a][b] = (f32x4){0.f, 0.f, 0.f, 0.f};

  for (int k0 = 0; k0 < D_MODEL; k0 += 64) {
#pragma unroll
    for (int c = 0; c < 4; ++c) {
      async16(ap[c], adst[c]);
      async16(bp[c], bdst[c]);
      ap[c] += 64; bp[c] += 64;
    }
    __syncthreads();
#pragma unroll
    for (int kk = 0; kk < 64; kk += 32) {
      const int gsw = (((kk >> 3) + q) ^ r7) * 8;   // swizzled col offset
      short8 af[4], bfg[4];
#pragma unroll
      for (int t = 0; t < 4; ++t)
        af[t] = *(const short8*)(As + (wm * 64 + t * 16 + r) * 64 + gsw);
#pragma unroll
      for (int t = 0; t < 4; ++t)
        bfg[t] = *(const short8*)(Bs + (wn * 64 + t * 16 + r) * 64 + gsw);
#pragma unroll
      for (int tm = 0; tm < 4; ++tm)
#pragma unroll
        for (int tn = 0; tn < 4; ++tn)
          acc[tm][tn] = __builtin_amdgcn_mfma_f32_16x16x32_bf16(af[tm], bfg[tn], acc[tm][tn], 0, 0, 0);
    }
    __syncthreads();
  }

  float bv[4];
#pragma unroll
  for (int tn = 0; tn < 4; ++tn) bv[tn] = b1[e * D_FF + n0 + wn * 64 + tn * 16 + r];
#pragma unroll
  for (int tm = 0; tm < 4; ++tm) {
#pragma unroll
    for (int v = 0; v < 4; ++v) {
      const int i = wm * 64 + tm * 16 + q * 4 + v;
      if (m0 + i < cnt) {
        unsigned short* hrow = h + (size_t)(bs + m0 + i) * D_FF + n0 + wn * 64 + r;
#pragma unroll
        for (int tn = 0; tn < 4; ++tn)
          hrow[tn * 16] = f2bf(fmaxf(acc[tm][tn][v] + bv[tn], 0.f));
      }
    }
  }
}

// ---- GEMM2: sout[slot][tok] = gate * (h @ w2[e] + b2[e]) ----
__global__ __launch_bounds__(256) void gemm2_kernel(
    const unsigned short* __restrict__ h, const unsigned short* __restrict__ w2t,
    const float* __restrict__ b2,
    const int* __restrict__ counts, const int* __restrict__ base,
    const int* __restrict__ tok_list, const int* __restrict__ slot_list,
    const float* __restrict__ gate_list, float* __restrict__ sout) {
  const int e = blockIdx.x, nt = blockIdx.y, mt = blockIdx.z;
  const int cnt = counts[e];
  const int m0 = mt * 128;
  if (m0 >= cnt) return;
  const int n0 = nt * 128;
  const int bs = base[e];

  __shared__ __align__(16) unsigned short As[128 * 64];
  __shared__ __align__(16) unsigned short Bs[128 * 64];

  const int tid = threadIdx.x;
  const int wave = tid >> 6, lane = tid & 63;
  const int lrow = lane >> 3;
  const int scg  = (lane & 7) ^ lrow;

  const unsigned short* ap[4];
  const unsigned short* bp[4];
  unsigned short* adst[4];
  unsigned short* bdst[4];
#pragma unroll
  for (int c = 0; c < 4; ++c) {
    const int rr = wave * 32 + c * 8;
    const int arow = min(m0 + rr + lrow, cnt - 1);
    ap[c] = h + (size_t)(bs + arow) * D_FF + scg * 8;
    bp[c] = w2t + (size_t)e * D_MODEL * D_FF + (size_t)(n0 + rr + lrow) * D_FF + scg * 8;
    adst[c] = As + rr * 64;
    bdst[c] = Bs + rr * 64;
  }

  const int wm = wave & 1, wn = wave >> 1;
  const int q = lane >> 4, r = lane & 15;
  const int r7 = r & 7;

  f32x4 acc[4][4];
#pragma unroll
  for (int a = 0; a < 4; ++a)
#pragma unroll
    for (int b = 0; b < 4; ++b) acc[a][b] = (f32x4){0.f, 0.f, 0.f, 0.f};

  for (int k0 = 0; k0 < D_FF; k0 += 64) {
#pragma unroll
    for (int c = 0; c < 4; ++c) {
      async16(ap[c], adst[c]);
      async16(bp[c], bdst[c]);
      ap[c] += 64; bp[c] += 64;
    }
    __syncthreads();
#pragma unroll
    for (int kk = 0; kk < 64; kk += 32) {
      const int gsw = (((kk >> 3) + q) ^ r7) * 8;
      short8 af[4], bfg[4];
#pragma unroll
      for (int t = 0; t < 4; ++t)
        af[t] = *(const short8*)(As + (wm * 64 + t * 16 + r) * 64 + gsw);
#pragma unroll
      for (int t = 0; t < 4; ++t)
        bfg[t] = *(const short8*)(Bs + (wn * 64 + t * 16 + r) * 64 + gsw);
#pragma unroll
      for (int tm = 0; tm < 4; ++tm)
#pragma unroll
        for (int tn = 0; tn < 4; ++tn)
          acc[tm][tn] = __builtin_amdgcn_mfma_f32_16x16x32_bf16(af[tm], bfg[tn], acc[tm][tn], 0, 0, 0);
    }
    __syncthreads();
  }

  float bv[4];
#pragma unroll
  for (int tn = 0; tn < 4; ++tn) bv[tn] = b2[e * D_MODEL + n0 + wn * 64 + tn * 16 + r];
#pragma unroll
  for (int tm = 0; tm < 4; ++tm) {
#pragma unroll
    for (int v = 0; v < 4; ++v) {
      const int i = wm * 64 + tm * 16 + q * 4 + v;
      const int mrow = m0 + i;
      if (mrow < cnt) {
        const int idx = e * N_TOK + mrow;
        const int tok = tok_list[idx];
        const int sl = slot_list[idx];
        const float g = gate_list[idx];
        float* orow = sout + ((size_t)sl * N_TOK + tok) * D_MODEL + n0 + wn * 64 + r;
#pragma unroll
        for (int tn = 0; tn < 4; ++tn)
          orow[tn * 16] = (acc[tm][tn][v] + bv[tn]) * g;
      }
    }
  }
}

__global__ __launch_bounds__(256) void combine_kernel(
    const float* __restrict__ sout, float* __restrict__ y) {
  const int i = blockIdx.x * 256 + threadIdx.x;
  const float4 a = ((const float4*)sout)[i];
  const float4 b = ((const float4*)(sout + (size_t)N_TOK * D_MODEL))[i];
  float4 o;
  o.x = a.x + b.x; o.y = a.y + b.y; o.z = a.z + b.z; o.w = a.w + b.w;
  const float eps = 2.2204460492503131e-16f;
  if (o.x == 0.f) o.x = eps;
  if (o.y == 0.f) o.y = eps;
  if (o.z == 0.f) o.z = eps;
  if (o.w == 0.f) o.w = eps;
  ((float4*)y)[i] = o;
}

extern "C" void kernel_launch(void* const* d_in, const int* in_sizes, int n_in,
                              void* d_out, int out_size, void* d_ws, size_t ws_size,
                              hipStream_t stream) {
  const float* x     = (const float*)d_in[0];
  const float* noise = (const float*)d_in[1];
  const float* wg    = (const float*)d_in[2];
  const float* wn    = (const float*)d_in[3];
  const float* w1    = (const float*)d_in[4];
  const float* b1    = (const float*)d_in[5];
  const float* w2    = (const float*)d_in[6];
  const float* b2    = (const float*)d_in[7];
  float* out = (float*)d_out;

  char* ws = (char*)d_ws;
  int*   counts    = (int*)(ws + OFF_COUNTS);
  int*   base      = (int*)(ws + OFF_BASE);
  int*   sel       = (int*)(ws + OFF_SEL);
  float* g0a       = (float*)(ws + OFF_G0);
  int*   tok_list  = (int*)(ws + OFF_TOK);
  int*   slot_list = (int*)(ws + OFF_SLOT);
  float* gate_list = (float*)(ws + OFF_GATE);
  float* loadvec   = (float*)(ws + OFF_LOADV);
  unsigned short* xb  = (unsigned short*)(ws + OFF_XB);
  unsigned short* w1t = (unsigned short*)(ws + OFF_W1T);
  unsigned short* w2t = (unsigned short*)(ws + OFF_W2T);
  unsigned short* h   = (unsigned short*)(ws + OFF_H);
  float* sout = (float*)(ws + OFF_SOUT);

  convert_x_kernel<<<4096, 256, 0, stream>>>(x, xb, counts);
  transpose_bf16_kernel<<<dim3(D_FF / 32, D_MODEL / 32, N_EXP), 256, 0, stream>>>(w1, w1t, D_MODEL, D_FF);
  transpose_bf16_kernel<<<dim3(D_MODEL / 32, D_FF / 32, N_EXP), 256, 0, stream>>>(w2, w2t, D_FF, D_MODEL);
  gating_kernel<<<N_TOK / 4, 256, 0, stream>>>(x, noise, wg, wn, sel, g0a, loadvec);
  build_lists_kernel<<<N_TOK / 256, 256, 0, stream>>>(sel, g0a, counts, tok_list, slot_list, gate_list);
  loss_scan_kernel<<<1, 256, 0, stream>>>(counts, base, sel, g0a, loadvec,
                                          out + (size_t)N_TOK * D_MODEL);
  // blockIdx.x = expert -> XCD affinity (id%8 heuristic)
  gemm1_kernel<<<dim3(N_EXP, D_FF / 128, N_TOK / 128), 256, 0, stream>>>(
      xb, w1t, b1, counts, base, tok_list, h);
  gemm2_kernel<<<dim3(N_EXP, D_MODEL / 128, N_TOK / 128), 256, 0, stream>>>(
      h, w2t, b2, counts, base, tok_list, slot_list, gate_list, sout);
  combine_kernel<<<(N_TOK * D_MODEL / 4) / 256, 256, 0, stream>>>(sout, out);
}

// Round 4
// 350.403 us; speedup vs baseline: 1.3230x; 1.0235x over previous
//
#include <hip/hip_runtime.h>
#include <hip/hip_bf16.h>

#define N_TOK 4096
#define D_MODEL 1024
#define D_FF 2048
#define N_EXP 8

typedef __attribute__((ext_vector_type(8))) short short8;
typedef __attribute__((ext_vector_type(4))) float f32x4;

// ---- workspace layout (bytes) ----
#define OFF_COUNTS 0              // 8 int
#define OFF_BASE   64             // 8 int
#define OFF_SEL    128            // 4096 int   (e0 | e1<<8)
#define OFF_G0     16512          // 4096 float
#define OFF_TOK    32896          // 8*4096 int
#define OFF_SLOT   163968        // 8*4096 int
#define OFF_GATE   295040         // 8*4096 float
#define OFF_LOADV  426112         // 4096*8 float
#define OFF_XB     1048576        // 4096*1024 bf16 (8 MB)
#define OFF_W1T    9437184        // 8*2048*1024 bf16 (32 MB) [n][k]; dead after gemm1,
                                  // reused as gemm2 kh=1 partial buffers (2x16 MB fp32)
#define OFF_W2T    42991616       // 8*1024*2048 bf16 (32 MB)  [n][k]
#define OFF_H      76546048       // 8192*2048 bf16 (32 MB)
#define OFF_SOUT   110100480      // 2*4096*1024 float (32 MB) (gemm2 kh=0, slots 0/1)

__device__ __forceinline__ unsigned short f2bf(float f) {
  union { float f; unsigned u; } a; a.f = f;
  return (unsigned short)((a.u + 0x7FFFu + ((a.u >> 16) & 1u)) >> 16);
}

// async global -> LDS, 16B/lane; LDS dst = wave-uniform base (+ lane*16 by HW)
__device__ __forceinline__ void async16(const void* g, void* l) {
  __builtin_amdgcn_global_load_lds(
      (const __attribute__((address_space(1))) unsigned int*)g,
      (__attribute__((address_space(3))) unsigned int*)l, 16, 0, 0);
}

// ---- fp32 [E][K][N] -> bf16 [E][N][K], 64x64 tiles ----
__global__ __launch_bounds__(256) void transpose_bf16_kernel(
    const float* __restrict__ in, unsigned short* __restrict__ out, int K, int N) {
  __shared__ float tile[64][65];
  const int e = blockIdx.z;
  const int kb = blockIdx.y * 64, nb = blockIdx.x * 64;
  const int tid = threadIdx.x;
  const float* ine = in + (size_t)e * K * N;
  unsigned short* oute = out + (size_t)e * K * N;
  {
    const int c4 = tid & 15;            // float4 column group
    const int rr = tid >> 4;            // 0..15
#pragma unroll
    for (int i = 0; i < 4; ++i) {
      const int row = i * 16 + rr;
      const float4 v = *(const float4*)(ine + (size_t)(kb + row) * N + nb + c4 * 4);
      tile[row][c4 * 4 + 0] = v.x;
      tile[row][c4 * 4 + 1] = v.y;
      tile[row][c4 * 4 + 2] = v.z;
      tile[row][c4 * 4 + 3] = v.w;
    }
  }
  __syncthreads();
  {
    const int n = tid >> 2, seg = tid & 3;   // out row n, 16-elem segment
    unsigned short v[16];
#pragma unroll
    for (int j = 0; j < 16; ++j) v[j] = f2bf(tile[seg * 16 + j][n]);
    uint4* dst = (uint4*)(oute + (size_t)(nb + n) * K + kb + seg * 16);
    dst[0] = *(uint4*)&v[0];
    dst[1] = *(uint4*)&v[8];
  }
}

// ---- noisy top-k gating + fused x->bf16 conversion; zeroes counts ----
__global__ __launch_bounds__(256) void gating_kernel(
    const float* __restrict__ x, const float* __restrict__ noise,
    const float* __restrict__ wg, const float* __restrict__ wn,
    int* __restrict__ sel, float* __restrict__ g0out,
    float* __restrict__ loadvec, unsigned short* __restrict__ xb,
    int* __restrict__ counts) {
  if (blockIdx.x == 0 && threadIdx.x < N_EXP) counts[threadIdx.x] = 0;
  const int wave = threadIdx.x >> 6, lane = threadIdx.x & 63;
  const int t = blockIdx.x * 4 + wave;
  float ag[8], an[8];
#pragma unroll
  for (int e = 0; e < 8; ++e) { ag[e] = 0.f; an[e] = 0.f; }
  const float* xrow = x + (size_t)t * D_MODEL;
  for (int d = lane; d < D_MODEL; d += 64) {
    const float xv = xrow[d];
    const float4 wa = ((const float4*)(wg + (size_t)d * 8))[0];
    const float4 wb = ((const float4*)(wg + (size_t)d * 8))[1];
    const float4 na = ((const float4*)(wn + (size_t)d * 8))[0];
    const float4 nb = ((const float4*)(wn + (size_t)d * 8))[1];
    ag[0] += xv * wa.x; ag[1] += xv * wa.y; ag[2] += xv * wa.z; ag[3] += xv * wa.w;
    ag[4] += xv * wb.x; ag[5] += xv * wb.y; ag[6] += xv * wb.z; ag[7] += xv * wb.w;
    an[0] += xv * na.x; an[1] += xv * na.y; an[2] += xv * na.z; an[3] += xv * na.w;
    an[4] += xv * nb.x; an[5] += xv * nb.y; an[6] += xv * nb.z; an[7] += xv * nb.w;
  }
  // fused x -> bf16 (re-reads hot L1/L2 lines, vectorized)
  {
    const float4* xv4 = (const float4*)xrow;
    ushort4* xb4 = (ushort4*)(xb + (size_t)t * D_MODEL);
#pragma unroll
    for (int i = 0; i < 4; ++i) {
      const float4 v = xv4[lane + i * 64];
      ushort4 o;
      o.x = f2bf(v.x); o.y = f2bf(v.y); o.z = f2bf(v.z); o.w = f2bf(v.w);
      xb4[lane + i * 64] = o;
    }
  }
#pragma unroll
  for (int e = 0; e < 8; ++e) {
#pragma unroll
    for (int off = 32; off > 0; off >>= 1) {
      ag[e] += __shfl_xor(ag[e], off, 64);
      an[e] += __shfl_xor(an[e], off, 64);
    }
  }
  float clean[8], sd[8], nz[8];
#pragma unroll
  for (int e = 0; e < 8; ++e) {
    clean[e] = ag[e];
    float s = an[e];
    s = (s > 20.f) ? s : log1pf(expf(s));
    sd[e] = s + 0.01f;
    nz[e] = clean[e] + noise[t * 8 + e] * sd[e];
  }
  float v0 = -1e30f, v1 = -1e30f, v2 = -1e30f; int i0 = 0, i1 = 0;
#pragma unroll
  for (int e = 0; e < 8; ++e) {
    const float v = nz[e];
    if (v > v0)      { v2 = v1; v1 = v0; i1 = i0; v0 = v; i0 = e; }
    else if (v > v1) { v2 = v1; v1 = v; i1 = e; }
    else if (v > v2) { v2 = v; }
  }
  const float ex = expf(v1 - v0);
  const float g0 = 1.f / (1.f + ex);
  if (lane == 0) { sel[t] = i0 | (i1 << 8); g0out[t] = g0; }
  if (lane < 8) {
    const int e = lane;
    const bool is_in = nz[e] > v2;
    const float thr = is_in ? v2 : v1;
    const float z = (clean[e] - thr) / sd[e];
    loadvec[t * 8 + e] = 0.5f * erfcf(-z * 0.70710678118654752f);
  }
}

__global__ __launch_bounds__(256) void build_lists_kernel(
    const int* __restrict__ sel, const float* __restrict__ g0a,
    int* __restrict__ counts, int* __restrict__ tok_list,
    int* __restrict__ slot_list, float* __restrict__ gate_list) {
  __shared__ int hist[8], bbase[8];
  if (threadIdx.x < 8) hist[threadIdx.x] = 0;
  __syncthreads();
  const int t = blockIdx.x * 256 + threadIdx.x;
  const int s = sel[t];
  const int e0 = s & 255, e1 = (s >> 8) & 255;
  atomicAdd(&hist[e0], 1);
  atomicAdd(&hist[e1], 1);
  __syncthreads();
  if (threadIdx.x < 8) {
    bbase[threadIdx.x] = atomicAdd(&counts[threadIdx.x], hist[threadIdx.x]);
    hist[threadIdx.x] = 0;
  }
  __syncthreads();
  const float g = g0a[t];
  const int p0 = atomicAdd(&hist[e0], 1);
  const int idx0 = e0 * N_TOK + bbase[e0] + p0;
  tok_list[idx0] = t; slot_list[idx0] = 0; gate_list[idx0] = g;
  const int p1 = atomicAdd(&hist[e1], 1);
  const int idx1 = e1 * N_TOK + bbase[e1] + p1;
  tok_list[idx1] = t; slot_list[idx1] = 1; gate_list[idx1] = 1.f - g;
}

__global__ __launch_bounds__(256) void loss_scan_kernel(
    const int* __restrict__ counts, int* __restrict__ base,
    const int* __restrict__ sel, const float* __restrict__ g0a,
    const float* __restrict__ loadvec, float* __restrict__ loss_out) {
  float limp[8], lld[8];
#pragma unroll
  for (int e = 0; e < 8; ++e) { limp[e] = 0.f; lld[e] = 0.f; }
  for (int t = threadIdx.x; t < N_TOK; t += 256) {
    const int s = sel[t];
    const float g = g0a[t];
    const int e0 = s & 255, e1 = (s >> 8) & 255;
#pragma unroll
    for (int e = 0; e < 8; ++e)
      limp[e] += (e0 == e ? g : 0.f) + (e1 == e ? (1.f - g) : 0.f);
#pragma unroll
    for (int e = 0; e < 8; ++e) lld[e] += loadvec[t * 8 + e];
  }
#pragma unroll
  for (int e = 0; e < 8; ++e) {
#pragma unroll
    for (int off = 32; off > 0; off >>= 1) {
      limp[e] += __shfl_xor(limp[e], off, 64);
      lld[e]  += __shfl_xor(lld[e],  off, 64);
    }
  }
  __shared__ float red[4][16];
  const int wave = threadIdx.x >> 6, lane = threadIdx.x & 63;
  if (lane == 0) {
#pragma unroll
    for (int e = 0; e < 8; ++e) { red[wave][e] = limp[e]; red[wave][8 + e] = lld[e]; }
  }
  __syncthreads();
  if (threadIdx.x == 0) {
    double imp[8], ld[8];
    for (int e = 0; e < 8; ++e) {
      imp[e] = (double)red[0][e] + red[1][e] + red[2][e] + red[3][e];
      ld[e]  = (double)red[0][8 + e] + red[1][8 + e] + red[2][8 + e] + red[3][8 + e];
    }
    double mi = 0, ml = 0;
    for (int e = 0; e < 8; ++e) { mi += imp[e]; ml += ld[e]; }
    mi /= 8.0; ml /= 8.0;
    double vi = 0, vl = 0;
    for (int e = 0; e < 8; ++e) { vi += (imp[e] - mi) * (imp[e] - mi); vl += (ld[e] - ml) * (ld[e] - ml); }
    vi /= 7.0; vl /= 7.0;
    const double loss = 0.1 * (vi / (mi * mi + 1e-10) + vl / (ml * ml + 1e-10));
    loss_out[0] = (float)loss;
    int b = 0;
    for (int e = 0; e < 8; ++e) { base[e] = b; b += counts[e]; }
  }
}

// ---- GEMM1: h = relu(gather(x) @ w1[e] + b1[e]); XOR-swizzled LDS ----
__global__ __launch_bounds__(256) void gemm1_kernel(
    const unsigned short* __restrict__ xb, const unsigned short* __restrict__ w1t,
    const float* __restrict__ b1,
    const int* __restrict__ counts, const int* __restrict__ base,
    const int* __restrict__ tok_list, unsigned short* __restrict__ h) {
  const int e = blockIdx.x, nt = blockIdx.y, mt = blockIdx.z;
  const int cnt = counts[e];
  const int m0 = mt * 128;
  if (m0 >= cnt) return;
  const int n0 = nt * 128;
  const int bs = base[e];

  __shared__ __align__(16) unsigned short As[128 * 64];
  __shared__ __align__(16) unsigned short Bs[128 * 64];

  const int tid = threadIdx.x;
  const int wave = tid >> 6, lane = tid & 63;
  const int lrow = lane >> 3;
  const int scg  = (lane & 7) ^ lrow;    // swizzled source column-group

  const unsigned short* ap[4];
  const unsigned short* bp[4];
  unsigned short* adst[4];
  unsigned short* bdst[4];
#pragma unroll
  for (int c = 0; c < 4; ++c) {
    const int rr = wave * 32 + c * 8;
    const int arow = min(m0 + rr + lrow, cnt - 1);
    const int tok = tok_list[e * N_TOK + arow];
    ap[c] = xb + (size_t)tok * D_MODEL + scg * 8;
    bp[c] = w1t + (size_t)e * D_MODEL * D_FF + (size_t)(n0 + rr + lrow) * D_MODEL + scg * 8;
    adst[c] = As + rr * 64;
    bdst[c] = Bs + rr * 64;
  }

  const int wm = wave & 1, wn = wave >> 1;
  const int q = lane >> 4, r = lane & 15;
  const int r7 = r & 7;

  f32x4 acc[4][4];
#pragma unroll
  for (int a = 0; a < 4; ++a)
#pragma unroll
    for (int b = 0; b < 4; ++b) acc[a][b] = (f32x4){0.f, 0.f, 0.f, 0.f};

  for (int k0 = 0; k0 < D_MODEL; k0 += 64) {
#pragma unroll
    for (int c = 0; c < 4; ++c) {
      async16(ap[c], adst[c]);
      async16(bp[c], bdst[c]);
      ap[c] += 64; bp[c] += 64;
    }
    __syncthreads();
#pragma unroll
    for (int kk = 0; kk < 64; kk += 32) {
      const int gsw = (((kk >> 3) + q) ^ r7) * 8;
      short8 af[4], bfg[4];
#pragma unroll
      for (int t = 0; t < 4; ++t)
        af[t] = *(const short8*)(As + (wm * 64 + t * 16 + r) * 64 + gsw);
#pragma unroll
      for (int t = 0; t < 4; ++t)
        bfg[t] = *(const short8*)(Bs + (wn * 64 + t * 16 + r) * 64 + gsw);
#pragma unroll
      for (int tm = 0; tm < 4; ++tm)
#pragma unroll
        for (int tn = 0; tn < 4; ++tn)
          acc[tm][tn] = __builtin_amdgcn_mfma_f32_16x16x32_bf16(af[tm], bfg[tn], acc[tm][tn], 0, 0, 0);
    }
    __syncthreads();
  }

  float bv[4];
#pragma unroll
  for (int tn = 0; tn < 4; ++tn) bv[tn] = b1[e * D_FF + n0 + wn * 64 + tn * 16 + r];
#pragma unroll
  for (int tm = 0; tm < 4; ++tm) {
#pragma unroll
    for (int v = 0; v < 4; ++v) {
      const int i = wm * 64 + tm * 16 + q * 4 + v;
      if (m0 + i < cnt) {
        unsigned short* hrow = h + (size_t)(bs + m0 + i) * D_FF + n0 + wn * 64 + r;
#pragma unroll
        for (int tn = 0; tn < 4; ++tn)
          hrow[tn * 16] = f2bf(fmaxf(acc[tm][tn][v] + bv[tn], 0.f));
      }
    }
  }
}

// ---- GEMM2 (K-split 2-way): partial[kh][slot][tok] = gate * (h @ w2[e] [+ b2]) ----
__global__ __launch_bounds__(256) void gemm2_kernel(
    const unsigned short* __restrict__ h, const unsigned short* __restrict__ w2t,
    const float* __restrict__ b2,
    const int* __restrict__ counts, const int* __restrict__ base,
    const int* __restrict__ tok_list, const int* __restrict__ slot_list,
    const float* __restrict__ gate_list,
    float* __restrict__ sout0, float* __restrict__ sout1) {
  const int e = blockIdx.x, nt = blockIdx.y;
  const int mt = blockIdx.z >> 1, kh = blockIdx.z & 1;
  const int cnt = counts[e];
  const int m0 = mt * 128;
  if (m0 >= cnt) return;
  const int n0 = nt * 128;
  const int bs = base[e];
  const int kbase = kh * (D_FF / 2);

  __shared__ __align__(16) unsigned short As[128 * 64];
  __shared__ __align__(16) unsigned short Bs[128 * 64];

  const int tid = threadIdx.x;
  const int wave = tid >> 6, lane = tid & 63;
  const int lrow = lane >> 3;
  const int scg  = (lane & 7) ^ lrow;

  const unsigned short* ap[4];
  const unsigned short* bp[4];
  unsigned short* adst[4];
  unsigned short* bdst[4];
#pragma unroll
  for (int c = 0; c < 4; ++c) {
    const int rr = wave * 32 + c * 8;
    const int arow = min(m0 + rr + lrow, cnt - 1);
    ap[c] = h + (size_t)(bs + arow) * D_FF + kbase + scg * 8;
    bp[c] = w2t + (size_t)e * D_MODEL * D_FF + (size_t)(n0 + rr + lrow) * D_FF + kbase + scg * 8;
    adst[c] = As + rr * 64;
    bdst[c] = Bs + rr * 64;
  }

  const int wm = wave & 1, wn = wave >> 1;
  const int q = lane >> 4, r = lane & 15;
  const int r7 = r & 7;

  f32x4 acc[4][4];
#pragma unroll
  for (int a = 0; a < 4; ++a)
#pragma unroll
    for (int b = 0; b < 4; ++b) acc[a][b] = (f32x4){0.f, 0.f, 0.f, 0.f};

  for (int k0 = 0; k0 < D_FF / 2; k0 += 64) {
#pragma unroll
    for (int c = 0; c < 4; ++c) {
      async16(ap[c], adst[c]);
      async16(bp[c], bdst[c]);
      ap[c] += 64; bp[c] += 64;
    }
    __syncthreads();
#pragma unroll
    for (int kk = 0; kk < 64; kk += 32) {
      const int gsw = (((kk >> 3) + q) ^ r7) * 8;
      short8 af[4], bfg[4];
#pragma unroll
      for (int t = 0; t < 4; ++t)
        af[t] = *(const short8*)(As + (wm * 64 + t * 16 + r) * 64 + gsw);
#pragma unroll
      for (int t = 0; t < 4; ++t)
        bfg[t] = *(const short8*)(Bs + (wn * 64 + t * 16 + r) * 64 + gsw);
#pragma unroll
      for (int tm = 0; tm < 4; ++tm)
#pragma unroll
        for (int tn = 0; tn < 4; ++tn)
          acc[tm][tn] = __builtin_amdgcn_mfma_f32_16x16x32_bf16(af[tm], bfg[tn], acc[tm][tn], 0, 0, 0);
    }
    __syncthreads();
  }

  float bv[4];
#pragma unroll
  for (int tn = 0; tn < 4; ++tn)
    bv[tn] = (kh == 0) ? b2[e * D_MODEL + n0 + wn * 64 + tn * 16 + r] : 0.f;
  float* const souts = (kh == 0) ? sout0 : sout1;
#pragma unroll
  for (int tm = 0; tm < 4; ++tm) {
#pragma unroll
    for (int v = 0; v < 4; ++v) {
      const int i = wm * 64 + tm * 16 + q * 4 + v;
      const int mrow = m0 + i;
      if (mrow < cnt) {
        const int idx = e * N_TOK + mrow;
        const int tok = tok_list[idx];
        const int sl = slot_list[idx];
        const float g = gate_list[idx];
        float* orow = souts + ((size_t)sl * N_TOK + tok) * D_MODEL + n0 + wn * 64 + r;
#pragma unroll
        for (int tn = 0; tn < 4; ++tn)
          orow[tn * 16] = (acc[tm][tn][v] + bv[tn]) * g;
      }
    }
  }
}

// ---- combine 4 partial buffers, zero-fill with eps ----
__global__ __launch_bounds__(256) void combine_kernel(
    const float* __restrict__ sout0, const float* __restrict__ sout1,
    float* __restrict__ y) {
  const int i = blockIdx.x * 256 + threadIdx.x;
  const float4 a = ((const float4*)sout0)[i];
  const float4 b = ((const float4*)(sout0 + (size_t)N_TOK * D_MODEL))[i];
  const float4 c = ((const float4*)sout1)[i];
  const float4 d = ((const float4*)(sout1 + (size_t)N_TOK * D_MODEL))[i];
  float4 o;
  o.x = (a.x + c.x) + (b.x + d.x);
  o.y = (a.y + c.y) + (b.y + d.y);
  o.z = (a.z + c.z) + (b.z + d.z);
  o.w = (a.w + c.w) + (b.w + d.w);
  const float eps = 2.2204460492503131e-16f;
  if (o.x == 0.f) o.x = eps;
  if (o.y == 0.f) o.y = eps;
  if (o.z == 0.f) o.z = eps;
  if (o.w == 0.f) o.w = eps;
  ((float4*)y)[i] = o;
}

extern "C" void kernel_launch(void* const* d_in, const int* in_sizes, int n_in,
                              void* d_out, int out_size, void* d_ws, size_t ws_size,
                              hipStream_t stream) {
  const float* x     = (const float*)d_in[0];
  const float* noise = (const float*)d_in[1];
  const float* wg    = (const float*)d_in[2];
  const float* wn    = (const float*)d_in[3];
  const float* w1    = (const float*)d_in[4];
  const float* b1    = (const float*)d_in[5];
  const float* w2    = (const float*)d_in[6];
  const float* b2    = (const float*)d_in[7];
  float* out = (float*)d_out;

  char* ws = (char*)d_ws;
  int*   counts    = (int*)(ws + OFF_COUNTS);
  int*   base      = (int*)(ws + OFF_BASE);
  int*   sel       = (int*)(ws + OFF_SEL);
  float* g0a       = (float*)(ws + OFF_G0);
  int*   tok_list  = (int*)(ws + OFF_TOK);
  int*   slot_list = (int*)(ws + OFF_SLOT);
  float* gate_list = (float*)(ws + OFF_GATE);
  float* loadvec   = (float*)(ws + OFF_LOADV);
  unsigned short* xb  = (unsigned short*)(ws + OFF_XB);
  unsigned short* w1t = (unsigned short*)(ws + OFF_W1T);
  unsigned short* w2t = (unsigned short*)(ws + OFF_W2T);
  unsigned short* h   = (unsigned short*)(ws + OFF_H);
  float* sout0 = (float*)(ws + OFF_SOUT);   // gemm2 kh=0 (with bias), slots 0/1
  float* sout1 = (float*)(ws + OFF_W1T);    // gemm2 kh=1 partials (w1t is dead by then)

  gating_kernel<<<N_TOK / 4, 256, 0, stream>>>(x, noise, wg, wn, sel, g0a, loadvec, xb, counts);
  transpose_bf16_kernel<<<dim3(D_FF / 64, D_MODEL / 64, N_EXP), 256, 0, stream>>>(w1, w1t, D_MODEL, D_FF);
  transpose_bf16_kernel<<<dim3(D_MODEL / 64, D_FF / 64, N_EXP), 256, 0, stream>>>(w2, w2t, D_FF, D_MODEL);
  build_lists_kernel<<<N_TOK / 256, 256, 0, stream>>>(sel, g0a, counts, tok_list, slot_list, gate_list);
  loss_scan_kernel<<<1, 256, 0, stream>>>(counts, base, sel, g0a, loadvec,
                                          out + (size_t)N_TOK * D_MODEL);
  gemm1_kernel<<<dim3(N_EXP, D_FF / 128, N_TOK / 128), 256, 0, stream>>>(
      xb, w1t, b1, counts, base, tok_list, h);
  gemm2_kernel<<<dim3(N_EXP, D_MODEL / 128, (N_TOK / 128) * 2), 256, 0, stream>>>(
      h, w2t, b2, counts, base, tok_list, slot_list, gate_list, sout0, sout1);
  combine_kernel<<<(N_TOK * D_MODEL / 4) / 256, 256, 0, stream>>>(sout0, sout1, out);
}